// Round 11
// baseline (84.607 us; speedup 1.0000x reference)
//
#include <hip/hip_runtime.h>
#include <math.h>

#define NB 8
#define NHEADS 8
#define NDK 32
#define NDV 64
#define NSEQ 1024
#define NCIN 256

typedef __attribute__((ext_vector_type(8))) short bf16x8;
typedef __attribute__((ext_vector_type(4))) float f32x4;
typedef __attribute__((ext_vector_type(16))) float f32x16;

#define MFMA16(A, B, C) __builtin_amdgcn_mfma_f32_16x16x32_bf16(A, B, C, 0, 0, 0)
#define MFMA32(A, B, C) __builtin_amdgcn_mfma_f32_32x32x16_bf16(A, B, C, 0, 0, 0)

// log2e folded constants: logits2 = qk * (1/sqrt(32) * log2e) + pe * (sqrt(32) * log2e)
#define SC2 0.2550347873f
#define PE2 8.1611156f

__device__ __forceinline__ short f2bf(float f) {
    union { float f; unsigned u; } v; v.f = f;
    unsigned r = v.u + 0x7FFFu + ((v.u >> 16) & 1u);
    return (short)(r >> 16);
}

__device__ __forceinline__ unsigned cvt_pk_bf16(float lo, float hi) {
    unsigned r;
    asm("v_cvt_pk_bf16_f32 %0, %1, %2" : "=v"(r) : "v"(lo), "v"(hi));
    return r;
}

// async global->LDS, 16B/lane. LDS dest must be wave-uniform base (HW adds lane*16).
__device__ __forceinline__ void gload16(const short* g, short* l) {
    __builtin_amdgcn_global_load_lds(
        (const __attribute__((address_space(1))) void*)g,
        (__attribute__((address_space(3))) void*)l, 16, 0, 0);
}

// ---------------- K0: fold BN into weights, convert to bf16 ----------------
__global__ __launch_bounds__(256) void prep_kernel(
    const float* __restrict__ wq, const float* __restrict__ qg, const float* __restrict__ qb,
    const float* __restrict__ qm, const float* __restrict__ qv,
    const float* __restrict__ wk, const float* __restrict__ kg, const float* __restrict__ kb,
    const float* __restrict__ km, const float* __restrict__ kv,
    const float* __restrict__ wv, const float* __restrict__ vg, const float* __restrict__ vb,
    const float* __restrict__ vm, const float* __restrict__ vv,
    const float* __restrict__ wo,
    short* __restrict__ Wqkv, float* __restrict__ Bqkv, short* __restrict__ Wo)
{
    int row = blockIdx.x, t = threadIdx.x;
    if (row < 1024) {
        const float *w, *g, *be, *mu, *va; int o;
        if (row < 256)      { w = wq; o = row;       g = qg; be = qb; mu = qm; va = qv; }
        else if (row < 512) { w = wk; o = row - 256; g = kg; be = kb; mu = km; va = kv; }
        else                { w = wv; o = row - 512; g = vg; be = vb; mu = vm; va = vv; }
        float inv = g[o] * rsqrtf(va[o] + 1e-5f);
        Wqkv[row * NCIN + t] = f2bf(w[o * NCIN + t] * inv);
        if (t == 0) Bqkv[row] = be[o] - mu[o] * inv;
    } else {
        int o = row - 1024;
        Wo[o * 512 + t]       = f2bf(wo[o * 512 + t]);
        Wo[o * 512 + 256 + t] = f2bf(wo[o * 512 + 256 + t]);
    }
}

// ---------------- K1: x (b,c,p) f32 -> Xt (b,p,c) bf16 ----------------
__global__ __launch_bounds__(256) void transpose_kernel(const float* __restrict__ x, short* __restrict__ Xt)
{
    __shared__ float tile[64][65];
    int b = blockIdx.z, p0 = blockIdx.x * 64, c0 = blockIdx.y * 64;
    int t = threadIdx.x, tp = t & 63, tr = t >> 6;
    const float* xb = x + ((size_t)b * NCIN + c0) * NSEQ + p0;
#pragma unroll
    for (int i = 0; i < 16; ++i) {
        int cl = tr * 16 + i;
        tile[cl][tp] = xb[(size_t)cl * NSEQ + tp];
    }
    __syncthreads();
    short* xt = Xt + ((size_t)b * NSEQ + p0) * NCIN + c0;
#pragma unroll
    for (int i = 0; i < 16; ++i) {
        int pl = tr * 16 + i;
        xt[(size_t)pl * NCIN + tp] = f2bf(tile[tp][pl]);
    }
}

// ---------------- K2: QKV projection GEMM (global_load_lds staging) ----------------
__global__ __launch_bounds__(256) void qkv_gemm(
    const short* __restrict__ Xt, const short* __restrict__ Wqkv, const float* __restrict__ Bqkv,
    short* __restrict__ Qo, short* __restrict__ Ko, short* __restrict__ Vto)
{
    __shared__ short At[128][32];   // linear (global_load_lds writes base + lane*16)
    __shared__ short Bt[128][32];
    int b = blockIdx.z, p0 = blockIdx.x * 128, o0 = blockIdx.y * 128;
    int t = threadIdx.x, wave = t >> 6, lane = t & 63;
    int wr = wave >> 1, wc = wave & 1, lr = lane & 15, lg = lane >> 4;

    const short* Abase = Xt + ((size_t)b * NSEQ + p0) * NCIN;
    const short* Bbase = Wqkv + (size_t)o0 * NCIN;

    int srow = lane >> 2, scol = (lane & 3) * 8;
    int r0 = (wave * 2) * 16 + srow, r1 = (wave * 2 + 1) * 16 + srow;
    short* lA0 = &At[0][0] + (wave * 2) * 512;
    short* lA1 = &At[0][0] + (wave * 2 + 1) * 512;
    short* lB0 = &Bt[0][0] + (wave * 2) * 512;
    short* lB1 = &Bt[0][0] + (wave * 2 + 1) * 512;

    f32x4 acc[4][4];
#pragma unroll
    for (int m = 0; m < 4; ++m)
#pragma unroll
        for (int n = 0; n < 4; ++n) acc[m][n] = (f32x4){0.f, 0.f, 0.f, 0.f};

    for (int k0 = 0; k0 < NCIN; k0 += 32) {
        gload16(Abase + (size_t)r0 * NCIN + k0 + scol, lA0);
        gload16(Abase + (size_t)r1 * NCIN + k0 + scol, lA1);
        gload16(Bbase + (size_t)r0 * NCIN + k0 + scol, lB0);
        gload16(Bbase + (size_t)r1 * NCIN + k0 + scol, lB1);
        __syncthreads();
        bf16x8 af[4], bfr[4];
#pragma unroll
        for (int m = 0; m < 4; ++m) af[m] = *(const bf16x8*)&At[wr * 64 + m * 16 + lr][lg * 8];
#pragma unroll
        for (int n = 0; n < 4; ++n) bfr[n] = *(const bf16x8*)&Bt[wc * 64 + n * 16 + lr][lg * 8];
#pragma unroll
        for (int m = 0; m < 4; ++m)
#pragma unroll
            for (int n = 0; n < 4; ++n)
                acc[m][n] = MFMA16(af[m], bfr[n], acc[m][n]);
        __syncthreads();
    }

#pragma unroll
    for (int n = 0; n < 4; ++n) {
        int o = o0 + wc * 64 + n * 16 + lr;
        float bias = Bqkv[o];
#pragma unroll
        for (int m = 0; m < 4; ++m) {
            int pr = p0 + wr * 64 + m * 16 + lg * 4;
#pragma unroll
            for (int r = 0; r < 4; ++r) {
                float y = acc[m][n][r] + bias;
                short vv = f2bf(y);
                int p = pr + r;
                if (o < 256) {
                    int hh = o >> 5, d = o & 31;
                    Qo[(((size_t)b * NHEADS + hh) * NSEQ + p) * NDK + d] = vv;
                } else if (o < 512) {
                    int oo = o - 256, hh = oo >> 5, d = oo & 31;
                    Ko[(((size_t)b * NHEADS + hh) * NSEQ + p) * NDK + d] = vv;
                } else {
                    int oo = o - 512, hh = oo >> 6, d = oo & 63;
                    Vto[(((size_t)b * NHEADS + hh) * NDV + d) * NSEQ + p] = vv;
                }
            }
        }
    }
}

// ---------------- K3: flash attention (template: SPLIT=1 half-keys + ws partials,
//                       SPLIT=0 = proven R9 monolithic with in-kernel GELU epilogue) ----
template<int SPLIT>
__global__ __launch_bounds__(256) void attn_kernel(
    const short* __restrict__ Q, const short* __restrict__ K, const short* __restrict__ Vt,
    const float* __restrict__ pos_emb, short* __restrict__ Xg,
    _Float16* __restrict__ Pws, float* __restrict__ Lws)
{
    __shared__ float peR[32][64];
    __shared__ short Klds[2][64][36];    // [buf][key][d]
    __shared__ short Vlds[2][64][68];    // [buf][d][j]

    int bid = blockIdx.x;
    int h, half, qt, b;
    if constexpr (SPLIT) {
        h = bid & 7; half = (bid >> 3) & 1; qt = (bid >> 4) & 7; b = bid >> 7;
    } else {
        h = bid & 7; half = 0; qt = (bid >> 3) & 7; b = bid >> 6;
    }
    int strip = (b * 8 + h) * 8 + qt;    // [0,512)
    int t = threadIdx.x, wave = t >> 6, l = t & 63, ql = l & 31, hi = l >> 5;

    {   // build reversed bias table: peR[dr][y] = pe[dr*32 + |31-y|] * PE2
        int dr = t >> 3, y0 = (t & 7) * 8;
#pragma unroll
        for (int k = 0; k < 8; ++k) {
            int y = y0 + k;
            if (y < 63) {
                int d = 31 - y; d = d < 0 ? -d : d;
                peR[dr][y] = pos_emb[(dr * 32 + d) * NHEADS + h] * PE2;
            }
        }
    }

    size_t bh = (size_t)b * NHEADS + h;
    const short* Qb = Q + bh * NSEQ * NDK;
    const short* Kb = K + bh * NSEQ * NDK;
    const short* Vb = Vt + bh * NDV * NSEQ;

    int q0 = qt * 128 + wave * 32;
    int iq = q0 + ql;
    int qr = iq >> 5;
    int pebase = 31 - ql + 4 * hi;
    int kbase = half * 512;
    const int NJT = SPLIT ? 8 : 16;

    bf16x8 qf0 = *(const bf16x8*)(Qb + (size_t)iq * NDK + hi * 8);
    bf16x8 qf1 = *(const bf16x8*)(Qb + (size_t)iq * NDK + 16 + hi * 8);

    int krow = t >> 2, kcol = (t & 3) * 8;
    int vrow = t >> 3, vcol = (t & 7) * 8;

    // prologue: stage tile 0 into buf 0
    {
        int4 kreg  = *(const int4*)(Kb + (size_t)(kbase + krow) * NDK + kcol);
        int4 vreg0 = *(const int4*)(Vb + (size_t)vrow * NSEQ + kbase + vcol);
        int4 vreg1 = *(const int4*)(Vb + (size_t)(vrow + 32) * NSEQ + kbase + vcol);
        *(int4*)&Klds[0][krow][kcol] = kreg;
        *(int4*)&Vlds[0][vrow][vcol] = vreg0;
        *(int4*)&Vlds[0][vrow + 32][vcol] = vreg1;
    }
    __syncthreads();   // peR + tile 0 ready

    float lsum = 0.f;
    f32x16 O0, O1;
#pragma unroll
    for (int r = 0; r < 16; ++r) { O0[r] = 0.f; O1[r] = 0.f; }

    int cur = 0;
    for (int jt = 0; jt < NJT; ++jt) {
        int4 kreg, vreg0, vreg1;
        if (jt < NJT - 1) {   // issue next-tile loads early; latency hides under compute
            int j0n = kbase + (jt + 1) * 64;
            kreg  = *(const int4*)(Kb + (size_t)(j0n + krow) * NDK + kcol);
            vreg0 = *(const int4*)(Vb + (size_t)vrow * NSEQ + j0n + vcol);
            vreg1 = *(const int4*)(Vb + (size_t)(vrow + 32) * NSEQ + j0n + vcol);
        }

#pragma unroll
        for (int s = 0; s < 2; ++s) {
            int jr = (kbase + jt * 64 + s * 32) >> 5;
            bf16x8 kf0 = *(const bf16x8*)&Klds[cur][s * 32 + ql][hi * 8];
            bf16x8 kf1 = *(const bf16x8*)&Klds[cur][s * 32 + ql][16 + hi * 8];
            f32x16 S;
#pragma unroll
            for (int r = 0; r < 16; ++r) S[r] = 0.f;
            S = MFMA32(kf0, qf0, S);
            S = MFMA32(kf1, qf1, S);

            bf16x8 vf[4];
#pragma unroll
            for (int dn = 0; dn < 2; ++dn)
#pragma unroll
                for (int ks = 0; ks < 2; ++ks)
                    vf[dn * 2 + ks] = *(const bf16x8*)&Vlds[cur][dn * 32 + ql][s * 32 + ks * 16 + hi * 8];

            int drb = qr - jr; drb = drb < 0 ? -drb : drb;   // wave-uniform
            const float* per = &peR[drb][pebase];
#pragma unroll
            for (int r = 0; r < 16; ++r) {
                int jcr = (r & 3) + 8 * (r >> 2);
                S[r] = fmaf(S[r], SC2, per[jcr]);
            }

            // P = exp2(logits2), no shift (|logits2| << 127, shift-invariant)
#pragma unroll
            for (int r = 0; r < 16; ++r) S[r] = __builtin_amdgcn_exp2f(S[r]);

            {   // lsum: 15-add tree
                float a0 = S[0] + S[1],   a1 = S[2] + S[3];
                float a2 = S[4] + S[5],   a3 = S[6] + S[7];
                float a4 = S[8] + S[9],   a5 = S[10] + S[11];
                float a6 = S[12] + S[13], a7 = S[14] + S[15];
                float b0 = a0 + a1, b1 = a2 + a3, b2 = a4 + a5, b3 = a6 + a7;
                lsum += (b0 + b1) + (b2 + b3);
            }

            unsigned pk[4][2];
#pragma unroll
            for (int a = 0; a < 4; ++a)
#pragma unroll
                for (int u = 0; u < 2; ++u)
                    pk[a][u] = cvt_pk_bf16(S[4 * a + 2 * u], S[4 * a + 2 * u + 1]);

#pragma unroll
            for (int ks = 0; ks < 2; ++ks) {
                unsigned u0 = pk[2 * ks][0], u2 = pk[2 * ks + 1][0];
                unsigned u1 = pk[2 * ks][1], u3 = pk[2 * ks + 1][1];
                asm("v_permlane32_swap_b32 %0, %1" : "+v"(u0), "+v"(u2));
                asm("v_permlane32_swap_b32 %0, %1" : "+v"(u1), "+v"(u3));
                union { bf16x8 v; unsigned u[4]; } pf;
                pf.u[0] = u0; pf.u[1] = u1; pf.u[2] = u2; pf.u[3] = u3;
                O0 = MFMA32(vf[ks], pf.v, O0);
                O1 = MFMA32(vf[2 + ks], pf.v, O1);
            }
        }

        if (jt < NJT - 1) {
            *(int4*)&Klds[cur ^ 1][krow][kcol] = kreg;
            *(int4*)&Vlds[cur ^ 1][vrow][vcol] = vreg0;
            *(int4*)&Vlds[cur ^ 1][vrow + 32][vcol] = vreg1;
            __syncthreads();
            cur ^= 1;
        }
    }

    lsum += __shfl_xor(lsum, 32);
    float inv = 1.0f / lsum;

    if constexpr (SPLIT) {
        // write per-half-normalized O (f16) + lsum; layout P[half*512+strip][d 64][q 128]
        _Float16* Pd = Pws + ((size_t)(half * 512 + strip)) * 8192 + (wave * 32 + ql);
#pragma unroll
        for (int dn = 0; dn < 2; ++dn)
#pragma unroll
            for (int r = 0; r < 16; ++r) {
                int d = dn * 32 + (r & 3) + 8 * (r >> 2) + 4 * hi;
                Pd[d * 128] = (_Float16)((dn ? O1[r] : O0[r]) * inv);
            }
        if (hi == 0) Lws[(half * 512 + strip) * 128 + wave * 32 + ql] = lsum;
    } else {
        // per-wave epilogue: GELU in regs, transpose via private tb slab, 16B stores
        __shared__ short tb[4][32][68];
        short (*tw)[68] = tb[wave];
#pragma unroll
        for (int dn = 0; dn < 2; ++dn)
#pragma unroll
            for (int a = 0; a < 4; ++a) {
                short4 w;
#pragma unroll
                for (int bb = 0; bb < 4; ++bb) {
                    float v = (dn ? O1[4 * a + bb] : O0[4 * a + bb]) * inv;
                    v = 0.5f * v * (1.f + erff(v * 0.70710678118654752f));  // exact GELU
                    ((short*)&w)[bb] = f2bf(v);
                }
                *(short4*)&tw[ql][dn * 32 + 8 * a + 4 * hi] = w;
            }
#pragma unroll
        for (int c = 0; c < 4; ++c) {
            int4 val = *(const int4*)&tw[ql][(hi * 4 + c) * 8];
            *(int4*)(Xg + ((size_t)b * NSEQ + q0 + ql) * 512 + h * 64 + (hi * 4 + c) * 8) = val;
        }
    }
}

// ---------------- K3b: merge halves + GELU + pack bf16 -> Xg ----------------
__global__ __launch_bounds__(256) void merge_kernel(
    const _Float16* __restrict__ P, const float* __restrict__ L, short* __restrict__ Xg)
{
    __shared__ float wa[128], wb[128];
    __shared__ short T[128][72];   // [q][d] bf16, padded
    int s = blockIdx.x;            // strip = (b*8+h)*8+qt
    int b = s >> 6, h = (s >> 3) & 7, qt = s & 7;
    int q0 = qt * 128;
    int t = threadIdx.x;
    if (t < 128) {
        float la = L[s * 128 + t], lb = L[(512 + s) * 128 + t];
        float inv = 1.0f / (la + lb);
        wa[t] = la * inv; wb[t] = lb * inv;
    }
    __syncthreads();
    const _Float16* Pa = P + (size_t)s * 8192;
    const _Float16* Pb = P + (size_t)(512 + s) * 8192;
#pragma unroll
    for (int rep = 0; rep < 2; ++rep) {
        int e = rep * 4096 + t * 16;
        int d = e >> 7, qb = e & 127;   // 16 consecutive q at fixed d
        union { int4 v[2]; _Float16 hx[16]; } ua, ub;
        ua.v[0] = *(const int4*)(Pa + e); ua.v[1] = *(const int4*)(Pa + e + 8);
        ub.v[0] = *(const int4*)(Pb + e); ub.v[1] = *(const int4*)(Pb + e + 8);
#pragma unroll
        for (int i = 0; i < 16; ++i) {
            int q = qb + i;
            float v = wa[q] * (float)ua.hx[i] + wb[q] * (float)ub.hx[i];
            v = 0.5f * v * (1.f + erff(v * 0.70710678118654752f));  // exact GELU
            T[q][d] = f2bf(v);
        }
    }
    __syncthreads();
    int q = t >> 1, dh = (t & 1) * 32;
    short* dst = Xg + ((size_t)b * NSEQ + q0 + q) * 512 + h * 64 + dh;
#pragma unroll
    for (int k = 0; k < 4; ++k)
        *(int4*)(dst + k * 8) = *(const int4*)&T[q][dh + k * 8];
}

// ---------------- K4: output projection + bias + BN (128x64, global_load_lds staging) ----------------
__global__ __launch_bounds__(256) void out_gemm(
    const short* __restrict__ Xg, const short* __restrict__ Wo,
    const float* __restrict__ bo, const float* __restrict__ og, const float* __restrict__ ob,
    const float* __restrict__ om, const float* __restrict__ ov,
    float* __restrict__ out)
{
    __shared__ short At[128][32];   // linear
    __shared__ short Bt[64][32];
    int mt = blockIdx.x, nt = blockIdx.y;
    int t = threadIdx.x, wave = t >> 6, lane = t & 63;
    int wr = wave >> 1, wc = wave & 1, lr = lane & 15, lg = lane >> 4;
    int row0 = mt * 128, o0 = nt * 64;

    int srow = lane >> 2, scol = (lane & 3) * 8;
    int rA0 = (wave * 2) * 16 + srow, rA1 = (wave * 2 + 1) * 16 + srow;
    int rB  = wave * 16 + srow;
    short* lA0 = &At[0][0] + (wave * 2) * 512;
    short* lA1 = &At[0][0] + (wave * 2 + 1) * 512;
    short* lB  = &Bt[0][0] + wave * 512;

    f32x4 acc[4][2];
#pragma unroll
    for (int m = 0; m < 4; ++m)
#pragma unroll
        for (int n = 0; n < 2; ++n) acc[m][n] = (f32x4){0.f, 0.f, 0.f, 0.f};

    for (int k0 = 0; k0 < 512; k0 += 32) {
        gload16(Xg + (size_t)(row0 + rA0) * 512 + k0 + scol, lA0);
        gload16(Xg + (size_t)(row0 + rA1) * 512 + k0 + scol, lA1);
        gload16(Wo + (size_t)(o0 + rB) * 512 + k0 + scol, lB);
        __syncthreads();
        bf16x8 af[4], bfr[2];
#pragma unroll
        for (int m = 0; m < 4; ++m) af[m] = *(const bf16x8*)&At[wr * 64 + m * 16 + lr][lg * 8];
#pragma unroll
        for (int n = 0; n < 2; ++n) bfr[n] = *(const bf16x8*)&Bt[wc * 32 + n * 16 + lr][lg * 8];
#pragma unroll
        for (int m = 0; m < 4; ++m)
#pragma unroll
            for (int n = 0; n < 2; ++n)
                acc[m][n] = MFMA16(af[m], bfr[n], acc[m][n]);
        __syncthreads();
    }

    int b = row0 >> 10;
    int pbase = row0 & 1023;
#pragma unroll
    for (int n = 0; n < 2; ++n) {
        int o = o0 + wc * 32 + n * 16 + lr;
        float inv = og[o] * rsqrtf(ov[o] + 1e-5f);
        float off = bo[o] * inv + ob[o] - om[o] * inv;
        float* dst = out + ((size_t)b * 256 + o) * 1024 + pbase;
#pragma unroll
        for (int m = 0; m < 4; ++m)
#pragma unroll
            for (int r = 0; r < 4; ++r) {
                int p = wr * 64 + m * 16 + lg * 4 + r;
                dst[p] = acc[m][n][r] * inv + off;
            }
    }
}

// ---------------- launch ----------------
extern "C" void kernel_launch(void* const* d_in, const int* in_sizes, int n_in,
                              void* d_out, int out_size, void* d_ws, size_t ws_size,
                              hipStream_t stream) {
    const float* x     = (const float*)d_in[0];
    const float* wq    = (const float*)d_in[1];
    const float* qgam  = (const float*)d_in[2];
    const float* qbet  = (const float*)d_in[3];
    const float* qmu   = (const float*)d_in[4];
    const float* qvar  = (const float*)d_in[5];
    const float* wk    = (const float*)d_in[6];
    const float* kgam  = (const float*)d_in[7];
    const float* kbet  = (const float*)d_in[8];
    const float* kmu   = (const float*)d_in[9];
    const float* kvar  = (const float*)d_in[10];
    const float* wv    = (const float*)d_in[11];
    const float* vgam  = (const float*)d_in[12];
    const float* vbet  = (const float*)d_in[13];
    const float* vmu   = (const float*)d_in[14];
    const float* vvar  = (const float*)d_in[15];
    const float* wo    = (const float*)d_in[16];
    const float* bo    = (const float*)d_in[17];
    const float* ogam  = (const float*)d_in[18];
    const float* obet  = (const float*)d_in[19];
    const float* omu   = (const float*)d_in[20];
    const float* ovar  = (const float*)d_in[21];
    const float* pos_emb = (const float*)d_in[22];
    // d_in[23] pos_indices: recomputed analytically in-kernel

    char* ws = (char*)d_ws;
    short* Wqkv = (short*)(ws + 0);          // 524288
    float* Bqkv = (float*)(ws + 524288);     // 4096
    short* Wo   = (short*)(ws + 528384);     // 262144
    short* Xt   = (short*)(ws + 790528);     // 4 MB
    short* Qd   = (short*)(ws + 4984832);    // 4 MB
    short* Kd   = (short*)(ws + 9179136);    // 4 MB
    short* Vtd  = (short*)(ws + 13373440);   // 8 MB
    short* Xg   = (short*)(ws + 21762048);   // 8 MB (end 30150656)
    _Float16* Pws = (_Float16*)(ws + 30150656); // 16777216 (end 46927872)
    float* Lws  = (float*)(ws + 46927872);   // 524288 (end 47452160)
    const size_t NEED_SPLIT = 47452160;

    prep_kernel<<<1280, 256, 0, stream>>>(wq, qgam, qbet, qmu, qvar,
                                          wk, kgam, kbet, kmu, kvar,
                                          wv, vgam, vbet, vmu, vvar,
                                          wo, Wqkv, Bqkv, Wo);
    transpose_kernel<<<dim3(16, 4, NB), 256, 0, stream>>>(x, Xt);
    qkv_gemm<<<dim3(8, 8, NB), 256, 0, stream>>>(Xt, Wqkv, Bqkv, Qd, Kd, Vtd);
    if (ws_size >= NEED_SPLIT) {
        attn_kernel<1><<<1024, 256, 0, stream>>>(Qd, Kd, Vtd, pos_emb, Xg, Pws, Lws);
        merge_kernel<<<512, 256, 0, stream>>>(Pws, Lws, Xg);
    } else {
        attn_kernel<0><<<512, 256, 0, stream>>>(Qd, Kd, Vtd, pos_emb, Xg, Pws, Lws);
    }
    out_gemm<<<dim3(64, 4), 256, 0, stream>>>(Xg, Wo, bo, ogam, obet, omu, ovar, (float*)d_out);
}

// Round 12
// 73.071 us; speedup vs baseline: 1.1579x; 1.1579x over previous
//
#include <hip/hip_runtime.h>
#include <math.h>

#define NB 8
#define NHEADS 8
#define NDK 32
#define NDV 64
#define NSEQ 1024
#define NCIN 256

typedef __attribute__((ext_vector_type(8))) short bf16x8;
typedef __attribute__((ext_vector_type(4))) float f32x4;
typedef __attribute__((ext_vector_type(16))) float f32x16;

#define MFMA16(A, B, C) __builtin_amdgcn_mfma_f32_16x16x32_bf16(A, B, C, 0, 0, 0)
#define MFMA32(A, B, C) __builtin_amdgcn_mfma_f32_32x32x16_bf16(A, B, C, 0, 0, 0)

// log2e folded constants: logits2 = (q*SC2)·k + pe*PE2, SC2 pre-folded into Q weights
#define SC2 0.2550347873f
#define PE2 8.1611156f

__device__ __forceinline__ short f2bf(float f) {
    union { float f; unsigned u; } v; v.f = f;
    unsigned r = v.u + 0x7FFFu + ((v.u >> 16) & 1u);
    return (short)(r >> 16);
}

__device__ __forceinline__ unsigned cvt_pk_bf16(float lo, float hi) {
    unsigned r;
    asm("v_cvt_pk_bf16_f32 %0, %1, %2" : "=v"(r) : "v"(lo), "v"(hi));
    return r;
}

// async global->LDS, 16B/lane. LDS dest must be wave-uniform base (HW adds lane*16).
__device__ __forceinline__ void gload16(const short* g, short* l) {
    __builtin_amdgcn_global_load_lds(
        (const __attribute__((address_space(1))) void*)g,
        (__attribute__((address_space(3))) void*)l, 16, 0, 0);
}

// ---------------- K0: fused {x transpose} + {BN fold + bf16 convert} ----------------
// blocks [0,512): transpose x (b,c,p) f32 -> Xt (b,p,c) bf16
// blocks [512,1792): fold BN into W rows (Q rows pre-scaled by SC2), convert Wo
__global__ __launch_bounds__(256) void prep_trans_kernel(
    const float* __restrict__ x, short* __restrict__ Xt,
    const float* __restrict__ wq, const float* __restrict__ qg, const float* __restrict__ qb,
    const float* __restrict__ qm, const float* __restrict__ qv,
    const float* __restrict__ wk, const float* __restrict__ kg, const float* __restrict__ kb,
    const float* __restrict__ km, const float* __restrict__ kv,
    const float* __restrict__ wv, const float* __restrict__ vg, const float* __restrict__ vb,
    const float* __restrict__ vm, const float* __restrict__ vv,
    const float* __restrict__ wo,
    short* __restrict__ Wqkv, float* __restrict__ Bqkv, short* __restrict__ Wo)
{
    __shared__ float tile[64][65];
    int bid = blockIdx.x, t = threadIdx.x;
    if (bid < 512) {
        int p0 = (bid & 15) * 64, c0 = ((bid >> 4) & 3) * 64, b = bid >> 6;
        int tp = t & 63, tr = t >> 6;
        const float* xb = x + ((size_t)b * NCIN + c0) * NSEQ + p0;
#pragma unroll
        for (int i = 0; i < 16; ++i) {
            int cl = tr * 16 + i;
            tile[cl][tp] = xb[(size_t)cl * NSEQ + tp];
        }
        __syncthreads();
        short* xt = Xt + ((size_t)b * NSEQ + p0) * NCIN + c0;
#pragma unroll
        for (int i = 0; i < 16; ++i) {
            int pl = tr * 16 + i;
            xt[(size_t)pl * NCIN + tp] = f2bf(tile[tp][pl]);
        }
    } else {
        int row = bid - 512;
        if (row < 1024) {
            const float *w, *g, *be, *mu, *va; int o; float sc;
            if (row < 256)      { w = wq; o = row;       g = qg; be = qb; mu = qm; va = qv; sc = SC2; }
            else if (row < 512) { w = wk; o = row - 256; g = kg; be = kb; mu = km; va = kv; sc = 1.f; }
            else                { w = wv; o = row - 512; g = vg; be = vb; mu = vm; va = vv; sc = 1.f; }
            float inv = g[o] * rsqrtf(va[o] + 1e-5f) * sc;
            Wqkv[row * NCIN + t] = f2bf(w[o * NCIN + t] * inv);
            if (t == 0) Bqkv[row] = (be[o] - mu[o] * (g[o] * rsqrtf(va[o] + 1e-5f))) * sc;
        } else {
            int o = row - 1024;
            Wo[o * 512 + t]       = f2bf(wo[o * 512 + t]);
            Wo[o * 512 + 256 + t] = f2bf(wo[o * 512 + 256 + t]);
        }
    }
}

// ---------------- K2: QKV projection GEMM (global_load_lds staging) ----------------
__global__ __launch_bounds__(256) void qkv_gemm(
    const short* __restrict__ Xt, const short* __restrict__ Wqkv, const float* __restrict__ Bqkv,
    short* __restrict__ Qo, short* __restrict__ Ko, short* __restrict__ Vto)
{
    __shared__ short At[128][32];   // linear (global_load_lds writes base + lane*16)
    __shared__ short Bt[128][32];
    int b = blockIdx.z, p0 = blockIdx.x * 128, o0 = blockIdx.y * 128;
    int t = threadIdx.x, wave = t >> 6, lane = t & 63;
    int wr = wave >> 1, wc = wave & 1, lr = lane & 15, lg = lane >> 4;

    const short* Abase = Xt + ((size_t)b * NSEQ + p0) * NCIN;
    const short* Bbase = Wqkv + (size_t)o0 * NCIN;

    int srow = lane >> 2, scol = (lane & 3) * 8;
    int r0 = (wave * 2) * 16 + srow, r1 = (wave * 2 + 1) * 16 + srow;
    short* lA0 = &At[0][0] + (wave * 2) * 512;
    short* lA1 = &At[0][0] + (wave * 2 + 1) * 512;
    short* lB0 = &Bt[0][0] + (wave * 2) * 512;
    short* lB1 = &Bt[0][0] + (wave * 2 + 1) * 512;

    f32x4 acc[4][4];
#pragma unroll
    for (int m = 0; m < 4; ++m)
#pragma unroll
        for (int n = 0; n < 4; ++n) acc[m][n] = (f32x4){0.f, 0.f, 0.f, 0.f};

    for (int k0 = 0; k0 < NCIN; k0 += 32) {
        gload16(Abase + (size_t)r0 * NCIN + k0 + scol, lA0);
        gload16(Abase + (size_t)r1 * NCIN + k0 + scol, lA1);
        gload16(Bbase + (size_t)r0 * NCIN + k0 + scol, lB0);
        gload16(Bbase + (size_t)r1 * NCIN + k0 + scol, lB1);
        __syncthreads();
        bf16x8 af[4], bfr[4];
#pragma unroll
        for (int m = 0; m < 4; ++m) af[m] = *(const bf16x8*)&At[wr * 64 + m * 16 + lr][lg * 8];
#pragma unroll
        for (int n = 0; n < 4; ++n) bfr[n] = *(const bf16x8*)&Bt[wc * 64 + n * 16 + lr][lg * 8];
#pragma unroll
        for (int m = 0; m < 4; ++m)
#pragma unroll
            for (int n = 0; n < 4; ++n)
                acc[m][n] = MFMA16(af[m], bfr[n], acc[m][n]);
        __syncthreads();
    }

#pragma unroll
    for (int n = 0; n < 4; ++n) {
        int o = o0 + wc * 64 + n * 16 + lr;
        float bias = Bqkv[o];
#pragma unroll
        for (int m = 0; m < 4; ++m) {
            int pr = p0 + wr * 64 + m * 16 + lg * 4;
#pragma unroll
            for (int r = 0; r < 4; ++r) {
                float y = acc[m][n][r] + bias;
                short vv = f2bf(y);
                int p = pr + r;
                if (o < 256) {
                    int hh = o >> 5, d = o & 31;
                    Qo[(((size_t)b * NHEADS + hh) * NSEQ + p) * NDK + d] = vv;
                } else if (o < 512) {
                    int oo = o - 256, hh = oo >> 5, d = oo & 31;
                    Ko[(((size_t)b * NHEADS + hh) * NSEQ + p) * NDK + d] = vv;
                } else {
                    int oo = o - 512, hh = oo >> 6, d = oo & 63;
                    Vto[(((size_t)b * NHEADS + hh) * NDV + d) * NSEQ + p] = vv;
                }
            }
        }
    }
}

// ---------------- K3: flash attention + GELU (R9 structure, bias-in-accumulator) ----------------
// WG = 4 waves x 32q = 128 q-rows of one (b,h); sweep 1024 keys in 64-key tiles.
// Q pre-scaled by SC2 -> S = MFMA(kf1,qf1, MFMA(kf0,qf0, C_bias)) -> exp2 directly:
// no S zero-init movs, no bias FMA stage (shorter serial chain, ~18% fewer VALU slots).
__global__ __launch_bounds__(256) void attn_kernel(
    const short* __restrict__ Q, const short* __restrict__ K, const short* __restrict__ Vt,
    const float* __restrict__ pos_emb, short* __restrict__ Xg)
{
    __shared__ float peR[32][64];
    __shared__ short Klds[2][64][36];    // [buf][key][d]
    __shared__ short Vlds[2][64][68];    // [buf][d][j]
    __shared__ short tb[4][32][68];      // per-wave epilogue transpose

    int bid = blockIdx.x;
    int h = bid & 7;                     // head per XCD: K/V set 1.5MB/XCD (L2-fit)
    int qt = (bid >> 3) & 7;
    int b = bid >> 6;
    int t = threadIdx.x, wave = t >> 6, l = t & 63, ql = l & 31, hi = l >> 5;

    {   // build reversed bias table: peR[dr][y] = pe[dr*32 + |31-y|] * PE2
        int dr = t >> 3, y0 = (t & 7) * 8;
#pragma unroll
        for (int k = 0; k < 8; ++k) {
            int y = y0 + k;
            if (y < 63) {
                int d = 31 - y; d = d < 0 ? -d : d;
                peR[dr][y] = pos_emb[(dr * 32 + d) * NHEADS + h] * PE2;
            }
        }
    }

    size_t bh = (size_t)b * NHEADS + h;
    const short* Qb = Q + bh * NSEQ * NDK;
    const short* Kb = K + bh * NSEQ * NDK;
    const short* Vb = Vt + bh * NDV * NSEQ;

    int q0 = qt * 128 + wave * 32;
    int iq = q0 + ql;
    int qr = iq >> 5;
    int pebase = 31 - ql + 4 * hi;

    bf16x8 qf0 = *(const bf16x8*)(Qb + (size_t)iq * NDK + hi * 8);
    bf16x8 qf1 = *(const bf16x8*)(Qb + (size_t)iq * NDK + 16 + hi * 8);

    int krow = t >> 2, kcol = (t & 3) * 8;
    int vrow = t >> 3, vcol = (t & 7) * 8;

    // prologue: stage tile 0 into buf 0
    {
        int4 kreg  = *(const int4*)(Kb + (size_t)krow * NDK + kcol);
        int4 vreg0 = *(const int4*)(Vb + (size_t)vrow * NSEQ + vcol);
        int4 vreg1 = *(const int4*)(Vb + (size_t)(vrow + 32) * NSEQ + vcol);
        *(int4*)&Klds[0][krow][kcol] = kreg;
        *(int4*)&Vlds[0][vrow][vcol] = vreg0;
        *(int4*)&Vlds[0][vrow + 32][vcol] = vreg1;
    }
    __syncthreads();   // peR + tile 0 ready

    float lsum = 0.f;
    f32x16 O0, O1;
#pragma unroll
    for (int r = 0; r < 16; ++r) { O0[r] = 0.f; O1[r] = 0.f; }

    int cur = 0;
    for (int jt = 0; jt < 16; ++jt) {
        int4 kreg, vreg0, vreg1;
        if (jt < 15) {   // issue next-tile loads early; latency hides under compute
            int j0n = (jt + 1) * 64;
            kreg  = *(const int4*)(Kb + (size_t)(j0n + krow) * NDK + kcol);
            vreg0 = *(const int4*)(Vb + (size_t)vrow * NSEQ + j0n + vcol);
            vreg1 = *(const int4*)(Vb + (size_t)(vrow + 32) * NSEQ + j0n + vcol);
        }

#pragma unroll
        for (int s = 0; s < 2; ++s) {
            int jr = (jt * 64 + s * 32) >> 5;
            int drb = qr - jr; drb = drb < 0 ? -drb : drb;   // wave-uniform
            const float* per = &peR[drb][pebase];

            bf16x8 kf0 = *(const bf16x8*)&Klds[cur][s * 32 + ql][hi * 8];
            bf16x8 kf1 = *(const bf16x8*)&Klds[cur][s * 32 + ql][16 + hi * 8];

            // C-init = bias (S[r] needs per[jcr], jcr = (r&3)+8*(r>>2))
            f32x16 S;
#pragma unroll
            for (int a = 0; a < 4; ++a)
#pragma unroll
                for (int u = 0; u < 4; ++u)
                    S[4 * a + u] = per[8 * a + u];
            S = MFMA32(kf0, qf0, S);
            S = MFMA32(kf1, qf1, S);

            bf16x8 vf[4];
#pragma unroll
            for (int dn = 0; dn < 2; ++dn)
#pragma unroll
                for (int ks = 0; ks < 2; ++ks)
                    vf[dn * 2 + ks] = *(const bf16x8*)&Vlds[cur][dn * 32 + ql][s * 32 + ks * 16 + hi * 8];

            // P = exp2(logits2) directly (|logits2| << 127, shift-invariant)
#pragma unroll
            for (int r = 0; r < 16; ++r) S[r] = __builtin_amdgcn_exp2f(S[r]);

            {   // lsum: 15-add tree
                float a0 = S[0] + S[1],   a1 = S[2] + S[3];
                float a2 = S[4] + S[5],   a3 = S[6] + S[7];
                float a4 = S[8] + S[9],   a5 = S[10] + S[11];
                float a6 = S[12] + S[13], a7 = S[14] + S[15];
                float b0 = a0 + a1, b1 = a2 + a3, b2 = a4 + a5, b3 = a6 + a7;
                lsum += (b0 + b1) + (b2 + b3);
            }

            unsigned pk[4][2];
#pragma unroll
            for (int a = 0; a < 4; ++a)
#pragma unroll
                for (int u = 0; u < 2; ++u)
                    pk[a][u] = cvt_pk_bf16(S[4 * a + 2 * u], S[4 * a + 2 * u + 1]);

#pragma unroll
            for (int ks = 0; ks < 2; ++ks) {
                unsigned u0 = pk[2 * ks][0], u2 = pk[2 * ks + 1][0];
                unsigned u1 = pk[2 * ks][1], u3 = pk[2 * ks + 1][1];
                asm("v_permlane32_swap_b32 %0, %1" : "+v"(u0), "+v"(u2));
                asm("v_permlane32_swap_b32 %0, %1" : "+v"(u1), "+v"(u3));
                union { bf16x8 v; unsigned u[4]; } pf;
                pf.u[0] = u0; pf.u[1] = u1; pf.u[2] = u2; pf.u[3] = u3;
                O0 = MFMA32(vf[ks], pf.v, O0);
                O1 = MFMA32(vf[2 + ks], pf.v, O1);
            }
        }

        if (jt < 15) {
            // buf[cur^1]'s last readers finished before the PREVIOUS barrier:
            // one barrier per iteration suffices.
            *(int4*)&Klds[cur ^ 1][krow][kcol] = kreg;
            *(int4*)&Vlds[cur ^ 1][vrow][vcol] = vreg0;
            *(int4*)&Vlds[cur ^ 1][vrow + 32][vcol] = vreg1;
            __syncthreads();
            cur ^= 1;
        }
    }

    lsum += __shfl_xor(lsum, 32);
    float inv = 1.0f / lsum;

    // per-wave epilogue: GELU in regs, transpose via private tb slab, 16B stores
    short (*tw)[68] = tb[wave];
#pragma unroll
    for (int dn = 0; dn < 2; ++dn)
#pragma unroll
        for (int a = 0; a < 4; ++a) {
            short4 w;
#pragma unroll
            for (int bb = 0; bb < 4; ++bb) {
                float v = (dn ? O1[4 * a + bb] : O0[4 * a + bb]) * inv;
                v = 0.5f * v * (1.f + erff(v * 0.70710678118654752f));  // exact GELU
                ((short*)&w)[bb] = f2bf(v);
            }
            *(short4*)&tw[ql][dn * 32 + 8 * a + 4 * hi] = w;
        }
#pragma unroll
    for (int c = 0; c < 4; ++c) {
        int4 val = *(const int4*)&tw[ql][(hi * 4 + c) * 8];
        *(int4*)(Xg + ((size_t)b * NSEQ + q0 + ql) * 512 + h * 64 + (hi * 4 + c) * 8) = val;
    }
}

// ---------------- K4: output projection + bias + BN (128x64, global_load_lds staging) ----------------
__global__ __launch_bounds__(256) void out_gemm(
    const short* __restrict__ Xg, const short* __restrict__ Wo,
    const float* __restrict__ bo, const float* __restrict__ og, const float* __restrict__ ob,
    const float* __restrict__ om, const float* __restrict__ ov,
    float* __restrict__ out)
{
    __shared__ short At[128][32];   // linear
    __shared__ short Bt[64][32];
    int mt = blockIdx.x, nt = blockIdx.y;
    int t = threadIdx.x, wave = t >> 6, lane = t & 63;
    int wr = wave >> 1, wc = wave & 1, lr = lane & 15, lg = lane >> 4;
    int row0 = mt * 128, o0 = nt * 64;

    int srow = lane >> 2, scol = (lane & 3) * 8;
    int rA0 = (wave * 2) * 16 + srow, rA1 = (wave * 2 + 1) * 16 + srow;
    int rB  = wave * 16 + srow;
    short* lA0 = &At[0][0] + (wave * 2) * 512;
    short* lA1 = &At[0][0] + (wave * 2 + 1) * 512;
    short* lB  = &Bt[0][0] + wave * 512;

    f32x4 acc[4][2];
#pragma unroll
    for (int m = 0; m < 4; ++m)
#pragma unroll
        for (int n = 0; n < 2; ++n) acc[m][n] = (f32x4){0.f, 0.f, 0.f, 0.f};

    for (int k0 = 0; k0 < 512; k0 += 32) {
        gload16(Xg + (size_t)(row0 + rA0) * 512 + k0 + scol, lA0);
        gload16(Xg + (size_t)(row0 + rA1) * 512 + k0 + scol, lA1);
        gload16(Wo + (size_t)(o0 + rB) * 512 + k0 + scol, lB);
        __syncthreads();
        bf16x8 af[4], bfr[2];
#pragma unroll
        for (int m = 0; m < 4; ++m) af[m] = *(const bf16x8*)&At[wr * 64 + m * 16 + lr][lg * 8];
#pragma unroll
        for (int n = 0; n < 2; ++n) bfr[n] = *(const bf16x8*)&Bt[wc * 32 + n * 16 + lr][lg * 8];
#pragma unroll
        for (int m = 0; m < 4; ++m)
#pragma unroll
            for (int n = 0; n < 2; ++n)
                acc[m][n] = MFMA16(af[m], bfr[n], acc[m][n]);
        __syncthreads();
    }

    int b = row0 >> 10;
    int pbase = row0 & 1023;
#pragma unroll
    for (int n = 0; n < 2; ++n) {
        int o = o0 + wc * 32 + n * 16 + lr;
        float inv = og[o] * rsqrtf(ov[o] + 1e-5f);
        float off = bo[o] * inv + ob[o] - om[o] * inv;
        float* dst = out + ((size_t)b * 256 + o) * 1024 + pbase;
#pragma unroll
        for (int m = 0; m < 4; ++m)
#pragma unroll
            for (int r = 0; r < 4; ++r) {
                int p = wr * 64 + m * 16 + lg * 4 + r;
                dst[p] = acc[m][n][r] * inv + off;
            }
    }
}

// ---------------- launch ----------------
extern "C" void kernel_launch(void* const* d_in, const int* in_sizes, int n_in,
                              void* d_out, int out_size, void* d_ws, size_t ws_size,
                              hipStream_t stream) {
    const float* x     = (const float*)d_in[0];
    const float* wq    = (const float*)d_in[1];
    const float* qgam  = (const float*)d_in[2];
    const float* qbet  = (const float*)d_in[3];
    const float* qmu   = (const float*)d_in[4];
    const float* qvar  = (const float*)d_in[5];
    const float* wk    = (const float*)d_in[6];
    const float* kgam  = (const float*)d_in[7];
    const float* kbet  = (const float*)d_in[8];
    const float* kmu   = (const float*)d_in[9];
    const float* kvar  = (const float*)d_in[10];
    const float* wv    = (const float*)d_in[11];
    const float* vgam  = (const float*)d_in[12];
    const float* vbet  = (const float*)d_in[13];
    const float* vmu   = (const float*)d_in[14];
    const float* vvar  = (const float*)d_in[15];
    const float* wo    = (const float*)d_in[16];
    const float* bo    = (const float*)d_in[17];
    const float* ogam  = (const float*)d_in[18];
    const float* obet  = (const float*)d_in[19];
    const float* omu   = (const float*)d_in[20];
    const float* ovar  = (const float*)d_in[21];
    const float* pos_emb = (const float*)d_in[22];
    // d_in[23] pos_indices: recomputed analytically in-kernel

    char* ws = (char*)d_ws;
    short* Wqkv = (short*)(ws + 0);          // 524288
    float* Bqkv = (float*)(ws + 524288);     // 4096
    short* Wo   = (short*)(ws + 528384);     // 262144
    short* Xt   = (short*)(ws + 790528);     // 4 MB
    short* Qd   = (short*)(ws + 4984832);    // 4 MB
    short* Kd   = (short*)(ws + 9179136);    // 4 MB
    short* Vtd  = (short*)(ws + 13373440);   // 8 MB
    short* Xg   = (short*)(ws + 21762048);   // 8 MB (end 30150656)

    prep_trans_kernel<<<1792, 256, 0, stream>>>(x, Xt,
                                                wq, qgam, qbet, qmu, qvar,
                                                wk, kgam, kbet, kmu, kvar,
                                                wv, vgam, vbet, vmu, vvar,
                                                wo, Wqkv, Bqkv, Wo);
    qkv_gemm<<<dim3(8, 8, NB), 256, 0, stream>>>(Xt, Wqkv, Bqkv, Qd, Kd, Vtd);
    attn_kernel<<<512, 256, 0, stream>>>(Qd, Kd, Vtd, pos_emb, Xg);
    out_gemm<<<dim3(64, 4), 256, 0, stream>>>(Xg, Wo, bo, ogam, obet, omu, ovar, (float*)d_out);
}

// Round 13
// 71.932 us; speedup vs baseline: 1.1762x; 1.0158x over previous
//
#include <hip/hip_runtime.h>
#include <math.h>

#define NB 8
#define NHEADS 8
#define NDK 32
#define NDV 64
#define NSEQ 1024
#define NCIN 256

typedef __attribute__((ext_vector_type(8))) short bf16x8;
typedef __attribute__((ext_vector_type(4))) float f32x4;
typedef __attribute__((ext_vector_type(16))) float f32x16;

#define MFMA16(A, B, C) __builtin_amdgcn_mfma_f32_16x16x32_bf16(A, B, C, 0, 0, 0)
#define MFMA32(A, B, C) __builtin_amdgcn_mfma_f32_32x32x16_bf16(A, B, C, 0, 0, 0)

// log2e folded constants: logits2 = (q*SC2)·k + pe*PE2, SC2 pre-folded into Q weights
#define SC2 0.2550347873f
#define PE2 8.1611156f

__device__ __forceinline__ short f2bf(float f) {
    union { float f; unsigned u; } v; v.f = f;
    unsigned r = v.u + 0x7FFFu + ((v.u >> 16) & 1u);
    return (short)(r >> 16);
}

__device__ __forceinline__ unsigned cvt_pk_bf16(float lo, float hi) {
    unsigned r;
    asm("v_cvt_pk_bf16_f32 %0, %1, %2" : "=v"(r) : "v"(lo), "v"(hi));
    return r;
}

// async global->LDS, 16B/lane. LDS dest must be wave-uniform base (HW adds lane*16).
__device__ __forceinline__ void gload16(const short* g, short* l) {
    __builtin_amdgcn_global_load_lds(
        (const __attribute__((address_space(1))) void*)g,
        (__attribute__((address_space(3))) void*)l, 16, 0, 0);
}

// ---------------- K0: fused {x transpose} + {BN fold + bf16 convert} ----------------
__global__ __launch_bounds__(256) void prep_trans_kernel(
    const float* __restrict__ x, short* __restrict__ Xt,
    const float* __restrict__ wq, const float* __restrict__ qg, const float* __restrict__ qb,
    const float* __restrict__ qm, const float* __restrict__ qv,
    const float* __restrict__ wk, const float* __restrict__ kg, const float* __restrict__ kb,
    const float* __restrict__ km, const float* __restrict__ kv,
    const float* __restrict__ wv, const float* __restrict__ vg, const float* __restrict__ vb,
    const float* __restrict__ vm, const float* __restrict__ vv,
    const float* __restrict__ wo,
    short* __restrict__ Wqkv, float* __restrict__ Bqkv, short* __restrict__ Wo)
{
    __shared__ float tile[64][65];
    int bid = blockIdx.x, t = threadIdx.x;
    if (bid < 512) {
        int p0 = (bid & 15) * 64, c0 = ((bid >> 4) & 3) * 64, b = bid >> 6;
        int tp = t & 63, tr = t >> 6;
        const float* xb = x + ((size_t)b * NCIN + c0) * NSEQ + p0;
#pragma unroll
        for (int i = 0; i < 16; ++i) {
            int cl = tr * 16 + i;
            tile[cl][tp] = xb[(size_t)cl * NSEQ + tp];
        }
        __syncthreads();
        short* xt = Xt + ((size_t)b * NSEQ + p0) * NCIN + c0;
#pragma unroll
        for (int i = 0; i < 16; ++i) {
            int pl = tr * 16 + i;
            xt[(size_t)pl * NCIN + tp] = f2bf(tile[tp][pl]);
        }
    } else {
        int row = bid - 512;
        if (row < 1024) {
            const float *w, *g, *be, *mu, *va; int o; float sc;
            if (row < 256)      { w = wq; o = row;       g = qg; be = qb; mu = qm; va = qv; sc = SC2; }
            else if (row < 512) { w = wk; o = row - 256; g = kg; be = kb; mu = km; va = kv; sc = 1.f; }
            else                { w = wv; o = row - 512; g = vg; be = vb; mu = vm; va = vv; sc = 1.f; }
            float inv = g[o] * rsqrtf(va[o] + 1e-5f) * sc;
            Wqkv[row * NCIN + t] = f2bf(w[o * NCIN + t] * inv);
            if (t == 0) Bqkv[row] = (be[o] - mu[o] * (g[o] * rsqrtf(va[o] + 1e-5f))) * sc;
        } else {
            int o = row - 1024;
            Wo[o * 512 + t]       = f2bf(wo[o * 512 + t]);
            Wo[o * 512 + 256 + t] = f2bf(wo[o * 512 + 256 + t]);
        }
    }
}

// ---------------- K2: QKV projection GEMM (global_load_lds staging) ----------------
__global__ __launch_bounds__(256) void qkv_gemm(
    const short* __restrict__ Xt, const short* __restrict__ Wqkv, const float* __restrict__ Bqkv,
    short* __restrict__ Qo, short* __restrict__ Ko, short* __restrict__ Vto)
{
    __shared__ short At[128][32];
    __shared__ short Bt[128][32];
    int b = blockIdx.z, p0 = blockIdx.x * 128, o0 = blockIdx.y * 128;
    int t = threadIdx.x, wave = t >> 6, lane = t & 63;
    int wr = wave >> 1, wc = wave & 1, lr = lane & 15, lg = lane >> 4;

    const short* Abase = Xt + ((size_t)b * NSEQ + p0) * NCIN;
    const short* Bbase = Wqkv + (size_t)o0 * NCIN;

    int srow = lane >> 2, scol = (lane & 3) * 8;
    int r0 = (wave * 2) * 16 + srow, r1 = (wave * 2 + 1) * 16 + srow;
    short* lA0 = &At[0][0] + (wave * 2) * 512;
    short* lA1 = &At[0][0] + (wave * 2 + 1) * 512;
    short* lB0 = &Bt[0][0] + (wave * 2) * 512;
    short* lB1 = &Bt[0][0] + (wave * 2 + 1) * 512;

    f32x4 acc[4][4];
#pragma unroll
    for (int m = 0; m < 4; ++m)
#pragma unroll
        for (int n = 0; n < 4; ++n) acc[m][n] = (f32x4){0.f, 0.f, 0.f, 0.f};

    for (int k0 = 0; k0 < NCIN; k0 += 32) {
        gload16(Abase + (size_t)r0 * NCIN + k0 + scol, lA0);
        gload16(Abase + (size_t)r1 * NCIN + k0 + scol, lA1);
        gload16(Bbase + (size_t)r0 * NCIN + k0 + scol, lB0);
        gload16(Bbase + (size_t)r1 * NCIN + k0 + scol, lB1);
        __syncthreads();
        bf16x8 af[4], bfr[4];
#pragma unroll
        for (int m = 0; m < 4; ++m) af[m] = *(const bf16x8*)&At[wr * 64 + m * 16 + lr][lg * 8];
#pragma unroll
        for (int n = 0; n < 4; ++n) bfr[n] = *(const bf16x8*)&Bt[wc * 64 + n * 16 + lr][lg * 8];
#pragma unroll
        for (int m = 0; m < 4; ++m)
#pragma unroll
            for (int n = 0; n < 4; ++n)
                acc[m][n] = MFMA16(af[m], bfr[n], acc[m][n]);
        __syncthreads();
    }

#pragma unroll
    for (int n = 0; n < 4; ++n) {
        int o = o0 + wc * 64 + n * 16 + lr;
        float bias = Bqkv[o];
#pragma unroll
        for (int m = 0; m < 4; ++m) {
            int pr = p0 + wr * 64 + m * 16 + lg * 4;
#pragma unroll
            for (int r = 0; r < 4; ++r) {
                float y = acc[m][n][r] + bias;
                short vv = f2bf(y);
                int p = pr + r;
                if (o < 256) {
                    int hh = o >> 5, d = o & 31;
                    Qo[(((size_t)b * NHEADS + hh) * NSEQ + p) * NDK + d] = vv;
                } else if (o < 512) {
                    int oo = o - 256, hh = oo >> 5, d = oo & 31;
                    Ko[(((size_t)b * NHEADS + hh) * NSEQ + p) * NDK + d] = vv;
                } else {
                    int oo = o - 512, hh = oo >> 6, d = oo & 63;
                    Vto[(((size_t)b * NHEADS + hh) * NDV + d) * NSEQ + p] = vv;
                }
            }
        }
    }
}

// ---------------- K3: flash attention + GELU (2-deep prefetch, counted vmcnt) ----------------
// WG = 4 waves x 32q; sweep 1024 keys in 64-key tiles. Register staging with TWO
// in-flight load sets: at iteration t, issue loads(t+2), compute(t), write set(t+1)
// -> compiler waits vmcnt(3) (only set t+1's loads), set t+2 stays in flight ACROSS
// the barrier (T3/T4 counted-vmcnt discipline; never drains to 0 in-loop).
__global__ __launch_bounds__(256) void attn_kernel(
    const short* __restrict__ Q, const short* __restrict__ K, const short* __restrict__ Vt,
    const float* __restrict__ pos_emb, short* __restrict__ Xg)
{
    __shared__ float peR[32][64];
    __shared__ short Klds[2][64][36];    // [buf][key][d]
    __shared__ short Vlds[2][64][68];    // [buf][d][j]
    __shared__ short tb[4][32][68];      // per-wave epilogue transpose

    int bid = blockIdx.x;
    int h = bid & 7;                     // head per XCD: K/V set 1.5MB/XCD (L2-fit)
    int qt = (bid >> 3) & 7;
    int b = bid >> 6;
    int t = threadIdx.x, wave = t >> 6, l = t & 63, ql = l & 31, hi = l >> 5;

    {   // build reversed bias table: peR[dr][y] = pe[dr*32 + |31-y|] * PE2
        int dr = t >> 3, y0 = (t & 7) * 8;
#pragma unroll
        for (int k = 0; k < 8; ++k) {
            int y = y0 + k;
            if (y < 63) {
                int d = 31 - y; d = d < 0 ? -d : d;
                peR[dr][y] = pos_emb[(dr * 32 + d) * NHEADS + h] * PE2;
            }
        }
    }

    size_t bh = (size_t)b * NHEADS + h;
    const short* Qb = Q + bh * NSEQ * NDK;
    const short* Kb = K + bh * NSEQ * NDK;
    const short* Vb = Vt + bh * NDV * NSEQ;

    int q0 = qt * 128 + wave * 32;
    int iq = q0 + ql;
    int qr = iq >> 5;
    int pebase = 31 - ql + 4 * hi;

    bf16x8 qf0 = *(const bf16x8*)(Qb + (size_t)iq * NDK + hi * 8);
    bf16x8 qf1 = *(const bf16x8*)(Qb + (size_t)iq * NDK + 16 + hi * 8);

    int krow = t >> 2, kcol = (t & 3) * 8;
    int vrow = t >> 3, vcol = (t & 7) * 8;

    float lsum = 0.f;
    f32x16 O0, O1;
#pragma unroll
    for (int r = 0; r < 16; ++r) { O0[r] = 0.f; O1[r] = 0.f; }

    // per-tile compute (buf/jt_ runtime; LDS indexing only — no scratch risk)
    auto compute_tile = [&](int buf, int jt_) {
#pragma unroll
        for (int s = 0; s < 2; ++s) {
            int jr = jt_ * 2 + s;
            int drb = qr - jr; drb = drb < 0 ? -drb : drb;   // wave-uniform
            const float* per = &peR[drb][pebase];

            bf16x8 kf0 = *(const bf16x8*)&Klds[buf][s * 32 + ql][hi * 8];
            bf16x8 kf1 = *(const bf16x8*)&Klds[buf][s * 32 + ql][16 + hi * 8];

            // C-init = bias (S[r] needs per[jcr], jcr = (r&3)+8*(r>>2))
            f32x16 S;
#pragma unroll
            for (int a = 0; a < 4; ++a)
#pragma unroll
                for (int u = 0; u < 4; ++u)
                    S[4 * a + u] = per[8 * a + u];
            S = MFMA32(kf0, qf0, S);
            S = MFMA32(kf1, qf1, S);

            bf16x8 vf[4];
#pragma unroll
            for (int dn = 0; dn < 2; ++dn)
#pragma unroll
                for (int ks = 0; ks < 2; ++ks)
                    vf[dn * 2 + ks] = *(const bf16x8*)&Vlds[buf][dn * 32 + ql][s * 32 + ks * 16 + hi * 8];

            // P = exp2(logits2) directly (|logits2| << 127, shift-invariant)
#pragma unroll
            for (int r = 0; r < 16; ++r) S[r] = __builtin_amdgcn_exp2f(S[r]);

            {   // lsum: 15-add tree
                float a0 = S[0] + S[1],   a1 = S[2] + S[3];
                float a2 = S[4] + S[5],   a3 = S[6] + S[7];
                float a4 = S[8] + S[9],   a5 = S[10] + S[11];
                float a6 = S[12] + S[13], a7 = S[14] + S[15];
                float b0 = a0 + a1, b1 = a2 + a3, b2 = a4 + a5, b3 = a6 + a7;
                lsum += (b0 + b1) + (b2 + b3);
            }

            unsigned pk[4][2];
#pragma unroll
            for (int a = 0; a < 4; ++a)
#pragma unroll
                for (int u = 0; u < 2; ++u)
                    pk[a][u] = cvt_pk_bf16(S[4 * a + 2 * u], S[4 * a + 2 * u + 1]);

#pragma unroll
            for (int ks = 0; ks < 2; ++ks) {
                unsigned u0 = pk[2 * ks][0], u2 = pk[2 * ks + 1][0];
                unsigned u1 = pk[2 * ks][1], u3 = pk[2 * ks + 1][1];
                asm("v_permlane32_swap_b32 %0, %1" : "+v"(u0), "+v"(u2));
                asm("v_permlane32_swap_b32 %0, %1" : "+v"(u1), "+v"(u3));
                union { bf16x8 v; unsigned u[4]; } pf;
                pf.u[0] = u0; pf.u[1] = u1; pf.u[2] = u2; pf.u[3] = u3;
                O0 = MFMA32(vf[ks], pf.v, O0);
                O1 = MFMA32(vf[2 + ks], pf.v, O1);
            }
        }
    };

    // prologue: tile0 -> buf0; Ra = tile1 in flight
    int4 ka, va0, va1, kb2, vb0, vb1;
    {
        ka  = *(const int4*)(Kb + (size_t)krow * NDK + kcol);
        va0 = *(const int4*)(Vb + (size_t)vrow * NSEQ + vcol);
        va1 = *(const int4*)(Vb + (size_t)(vrow + 32) * NSEQ + vcol);
        *(int4*)&Klds[0][krow][kcol] = ka;
        *(int4*)&Vlds[0][vrow][vcol] = va0;
        *(int4*)&Vlds[0][vrow + 32][vcol] = va1;
        ka  = *(const int4*)(Kb + (size_t)(64 + krow) * NDK + kcol);
        va0 = *(const int4*)(Vb + (size_t)vrow * NSEQ + 64 + vcol);
        va1 = *(const int4*)(Vb + (size_t)(vrow + 32) * NSEQ + 64 + vcol);
    }
    __syncthreads();   // peR + tile 0 ready

    for (int jt = 0; jt < 16; jt += 2) {
        // EVEN phase: compute tile jt (buf0); Ra holds tile jt+1; issue Rb = tile jt+2
        if (jt + 2 < 16) {
            int j0n = (jt + 2) * 64;
            kb2 = *(const int4*)(Kb + (size_t)(j0n + krow) * NDK + kcol);
            vb0 = *(const int4*)(Vb + (size_t)vrow * NSEQ + j0n + vcol);
            vb1 = *(const int4*)(Vb + (size_t)(vrow + 32) * NSEQ + j0n + vcol);
        }
        __builtin_amdgcn_s_setprio(1);
        compute_tile(0, jt);
        __builtin_amdgcn_s_setprio(0);
        *(int4*)&Klds[1][krow][kcol] = ka;          // waits only Ra's loads (vmcnt(3))
        *(int4*)&Vlds[1][vrow][vcol] = va0;
        *(int4*)&Vlds[1][vrow + 32][vcol] = va1;
        __syncthreads();

        // ODD phase: compute tile jt+1 (buf1); Rb holds tile jt+2; issue Ra = tile jt+3
        if (jt + 3 < 16) {
            int j0n = (jt + 3) * 64;
            ka  = *(const int4*)(Kb + (size_t)(j0n + krow) * NDK + kcol);
            va0 = *(const int4*)(Vb + (size_t)vrow * NSEQ + j0n + vcol);
            va1 = *(const int4*)(Vb + (size_t)(vrow + 32) * NSEQ + j0n + vcol);
        }
        __builtin_amdgcn_s_setprio(1);
        compute_tile(1, jt + 1);
        __builtin_amdgcn_s_setprio(0);
        if (jt + 2 < 16) {
            *(int4*)&Klds[0][krow][kcol] = kb2;     // waits only Rb's loads
            *(int4*)&Vlds[0][vrow][vcol] = vb0;
            *(int4*)&Vlds[0][vrow + 32][vcol] = vb1;
            __syncthreads();
        }
    }

    lsum += __shfl_xor(lsum, 32);
    float inv = 1.0f / lsum;

    // per-wave epilogue: GELU in regs, transpose via private tb slab, 16B stores
    short (*tw)[68] = tb[wave];
#pragma unroll
    for (int dn = 0; dn < 2; ++dn)
#pragma unroll
        for (int a = 0; a < 4; ++a) {
            short4 w;
#pragma unroll
            for (int bb = 0; bb < 4; ++bb) {
                float v = (dn ? O1[4 * a + bb] : O0[4 * a + bb]) * inv;
                v = 0.5f * v * (1.f + erff(v * 0.70710678118654752f));  // exact GELU
                ((short*)&w)[bb] = f2bf(v);
            }
            *(short4*)&tw[ql][dn * 32 + 8 * a + 4 * hi] = w;
        }
#pragma unroll
    for (int c = 0; c < 4; ++c) {
        int4 val = *(const int4*)&tw[ql][(hi * 4 + c) * 8];
        *(int4*)(Xg + ((size_t)b * NSEQ + q0 + ql) * 512 + h * 64 + (hi * 4 + c) * 8) = val;
    }
}

// ---------------- K4: output projection + bias + BN (128x64, global_load_lds staging) ----------------
__global__ __launch_bounds__(256) void out_gemm(
    const short* __restrict__ Xg, const short* __restrict__ Wo,
    const float* __restrict__ bo, const float* __restrict__ og, const float* __restrict__ ob,
    const float* __restrict__ om, const float* __restrict__ ov,
    float* __restrict__ out)
{
    __shared__ short At[128][32];
    __shared__ short Bt[64][32];
    int mt = blockIdx.x, nt = blockIdx.y;
    int t = threadIdx.x, wave = t >> 6, lane = t & 63;
    int wr = wave >> 1, wc = wave & 1, lr = lane & 15, lg = lane >> 4;
    int row0 = mt * 128, o0 = nt * 64;

    int srow = lane >> 2, scol = (lane & 3) * 8;
    int rA0 = (wave * 2) * 16 + srow, rA1 = (wave * 2 + 1) * 16 + srow;
    int rB  = wave * 16 + srow;
    short* lA0 = &At[0][0] + (wave * 2) * 512;
    short* lA1 = &At[0][0] + (wave * 2 + 1) * 512;
    short* lB  = &Bt[0][0] + wave * 512;

    f32x4 acc[4][2];
#pragma unroll
    for (int m = 0; m < 4; ++m)
#pragma unroll
        for (int n = 0; n < 2; ++n) acc[m][n] = (f32x4){0.f, 0.f, 0.f, 0.f};

    for (int k0 = 0; k0 < 512; k0 += 32) {
        gload16(Xg + (size_t)(row0 + rA0) * 512 + k0 + scol, lA0);
        gload16(Xg + (size_t)(row0 + rA1) * 512 + k0 + scol, lA1);
        gload16(Wo + (size_t)(o0 + rB) * 512 + k0 + scol, lB);
        __syncthreads();
        bf16x8 af[4], bfr[2];
#pragma unroll
        for (int m = 0; m < 4; ++m) af[m] = *(const bf16x8*)&At[wr * 64 + m * 16 + lr][lg * 8];
#pragma unroll
        for (int n = 0; n < 2; ++n) bfr[n] = *(const bf16x8*)&Bt[wc * 32 + n * 16 + lr][lg * 8];
#pragma unroll
        for (int m = 0; m < 4; ++m)
#pragma unroll
            for (int n = 0; n < 2; ++n)
                acc[m][n] = MFMA16(af[m], bfr[n], acc[m][n]);
        __syncthreads();
    }

    int b = row0 >> 10;
    int pbase = row0 & 1023;
#pragma unroll
    for (int n = 0; n < 2; ++n) {
        int o = o0 + wc * 32 + n * 16 + lr;
        float inv = og[o] * rsqrtf(ov[o] + 1e-5f);
        float off = bo[o] * inv + ob[o] - om[o] * inv;
        float* dst = out + ((size_t)b * 256 + o) * 1024 + pbase;
#pragma unroll
        for (int m = 0; m < 4; ++m)
#pragma unroll
            for (int r = 0; r < 4; ++r) {
                int p = wr * 64 + m * 16 + lg * 4 + r;
                dst[p] = acc[m][n][r] * inv + off;
            }
    }
}

// ---------------- launch ----------------
extern "C" void kernel_launch(void* const* d_in, const int* in_sizes, int n_in,
                              void* d_out, int out_size, void* d_ws, size_t ws_size,
                              hipStream_t stream) {
    const float* x     = (const float*)d_in[0];
    const float* wq    = (const float*)d_in[1];
    const float* qgam  = (const float*)d_in[2];
    const float* qbet  = (const float*)d_in[3];
    const float* qmu   = (const float*)d_in[4];
    const float* qvar  = (const float*)d_in[5];
    const float* wk    = (const float*)d_in[6];
    const float* kgam  = (const float*)d_in[7];
    const float* kbet  = (const float*)d_in[8];
    const float* kmu   = (const float*)d_in[9];
    const float* kvar  = (const float*)d_in[10];
    const float* wv    = (const float*)d_in[11];
    const float* vgam  = (const float*)d_in[12];
    const float* vbet  = (const float*)d_in[13];
    const float* vmu   = (const float*)d_in[14];
    const float* vvar  = (const float*)d_in[15];
    const float* wo    = (const float*)d_in[16];
    const float* bo    = (const float*)d_in[17];
    const float* ogam  = (const float*)d_in[18];
    const float* obet  = (const float*)d_in[19];
    const float* omu   = (const float*)d_in[20];
    const float* ovar  = (const float*)d_in[21];
    const float* pos_emb = (const float*)d_in[22];
    // d_in[23] pos_indices: recomputed analytically in-kernel

    char* ws = (char*)d_ws;
    short* Wqkv = (short*)(ws + 0);          // 524288
    float* Bqkv = (float*)(ws + 524288);     // 4096
    short* Wo   = (short*)(ws + 528384);     // 262144
    short* Xt   = (short*)(ws + 790528);     // 4 MB
    short* Qd   = (short*)(ws + 4984832);    // 4 MB
    short* Kd   = (short*)(ws + 9179136);    // 4 MB
    short* Vtd  = (short*)(ws + 13373440);   // 8 MB
    short* Xg   = (short*)(ws + 21762048);   // 8 MB (end 30150656)

    prep_trans_kernel<<<1792, 256, 0, stream>>>(x, Xt,
                                                wq, qgam, qbet, qmu, qvar,
                                                wk, kgam, kbet, kmu, kvar,
                                                wv, vgam, vbet, vmu, vvar,
                                                wo, Wqkv, Bqkv, Wo);
    qkv_gemm<<<dim3(8, 8, NB), 256, 0, stream>>>(Xt, Wqkv, Bqkv, Qd, Kd, Vtd);
    attn_kernel<<<512, 256, 0, stream>>>(Qd, Kd, Vtd, pos_emb, Xg);
    out_gemm<<<dim3(64, 4), 256, 0, stream>>>(Xg, Wo, bo, ogam, obet, omu, ovar, (float*)d_out);
}